// Round 2
// baseline (325.113 us; speedup 1.0000x reference)
//
#include <hip/hip_runtime.h>

#define NB 4096   // B
#define NS 200    // S
#define NP 8      // P
#define NF 64     // F

__global__ __launch_bounds__(256) void cf_kernel(
    const int*   __restrict__ user,
    const int*   __restrict__ items,
    const float* __restrict__ user_factors,   // [N_USERS][P][F] fp32
    const float* __restrict__ item_factors,   // [N_ITEMS][F]    fp32
    float* __restrict__ out_pred,             // [B][S]          fp32
    float* __restrict__ out_scores)           // [B][S][P]       fp32
{
    __shared__ float u_lds[NF * NP];  // transposed: [f][p]

    const int b   = blockIdx.x;
    const int tid = threadIdx.x;

    // ---- stage user factors (512 fp32, 2KB) into LDS transposed [f][p] ----
    {
        const int uid = user[b];
        const float2* ub = (const float2*)(user_factors + (size_t)uid * (NP * NF));
        float2 w = ub[tid];              // elements 2*tid, 2*tid+1 (p-major)
        int e0 = tid * 2;
        int p0 = e0 >> 6, f0 = e0 & 63;
        u_lds[f0 * NP + p0] = w.x;
        int e1 = e0 + 1;
        int p1 = e1 >> 6, f1 = e1 & 63;
        u_lds[f1 * NP + p1] = w.y;
    }
    __syncthreads();

    const int s = tid;
    if (s >= NS) return;

    const int idx = items[b * NS + s];
    const float4* vp4 = (const float4*)(item_factors + (size_t)idx * NF);

    float r[NP];
    #pragma unroll
    for (int p = 0; p < NP; ++p) r[p] = 0.f;

    #pragma unroll
    for (int c = 0; c < NF / 8; ++c) {
        float4 v0 = vp4[2 * c];
        float4 v1 = vp4[2 * c + 1];
        float vf[8] = {v0.x, v0.y, v0.z, v0.w, v1.x, v1.y, v1.z, v1.w};
        #pragma unroll
        for (int j = 0; j < 8; ++j) {
            // wave-uniform LDS address -> broadcast, conflict-free; 2x ds_read_b128
            const float4* up = (const float4*)&u_lds[(c * 8 + j) * NP];
            float4 a  = up[0];
            float4 bb = up[1];
            float vv = vf[j];
            r[0] += vv * a.x;  r[1] += vv * a.y;  r[2] += vv * a.z;  r[3] += vv * a.w;
            r[4] += vv * bb.x; r[5] += vv * bb.y; r[6] += vv * bb.z; r[7] += vv * bb.w;
        }
    }

    // ---- softmax over P personas ----
    float m = r[0];
    #pragma unroll
    for (int p = 1; p < NP; ++p) m = fmaxf(m, r[p]);
    float e[NP];
    float sum = 0.f;
    #pragma unroll
    for (int p = 0; p < NP; ++p) { e[p] = __expf(r[p] - m); sum += e[p]; }
    float inv = 1.f / sum;

    // pred = sum_p score_p * r_p   (== dot(attentive_user, v))
    float sc[NP];
    float pred = 0.f;
    #pragma unroll
    for (int p = 0; p < NP; ++p) {
        sc[p] = e[p] * inv;
        pred += sc[p] * r[p];
    }

    out_pred[b * NS + s] = pred;
    float4* op = (float4*)(out_scores + (size_t)(b * NS + s) * NP);
    op[0] = make_float4(sc[0], sc[1], sc[2], sc[3]);
    op[1] = make_float4(sc[4], sc[5], sc[6], sc[7]);
}

extern "C" void kernel_launch(void* const* d_in, const int* in_sizes, int n_in,
                              void* d_out, int out_size, void* d_ws, size_t ws_size,
                              hipStream_t stream) {
    const int*   user         = (const int*)d_in[0];
    const int*   items        = (const int*)d_in[1];
    const float* user_factors = (const float*)d_in[2];
    const float* item_factors = (const float*)d_in[3];

    float* out_pred   = (float*)d_out;
    float* out_scores = out_pred + (size_t)NB * NS;   // outputs concatenated: pred, scores

    cf_kernel<<<NB, 256, 0, stream>>>(user, items, user_factors, item_factors,
                                      out_pred, out_scores);
}